// Round 1
// 764.012 us; speedup vs baseline: 1.0272x; 1.0272x over previous
//
#include <hip/hip_runtime.h>
#include <math.h>

#define Nn 100000
#define Ee 3200000
#define Hh 512
#define Bb 512
#define GIN 1028
#define PCH 4   // row-chunks per graph for pooling phase A

// ---------------- workspace layout (bytes) ----------------
#define OFF_STARTS 0                                   // (Bb+1) ints
#define OFF_NEDGE  4096                                // Bb ints
#define OFF_WL     8192                                // Bb floats
#define OFF_WG     10240                               // Bb floats
#define OFF_G      16384                               // Bb*GIN floats (row-major, 1028/row)
#define OFF_PP     (OFF_G + (size_t)Bb*GIN*4)          // PCH * Bb * 1024 floats (pool partials)
#define OFF_HPART  (OFF_PP + (size_t)PCH*Bb*1024*4)    // 4 * Bb*Hh floats (split-K partials)
#define OFF_H      (OFF_HPART + (size_t)4*Bb*Hh*4)     // Bb*Hh floats (post-LN+ReLU)
#define OFF_HP2    (OFF_H + (size_t)Bb*Hh*4)           // 2 * Bb*256 floats (layer2 split-K partials)
// total ~16.8 MB

// ---------------- segment starts via binary search (batch is sorted) ----------------
__global__ void k_starts(const int* __restrict__ batch, int* __restrict__ starts) {
    int t = threadIdx.x;
    for (int b = t; b <= Bb; b += blockDim.x) {
        int lo = 0, hi = Nn;
        while (lo < hi) { int mid = (lo + hi) >> 1; if (batch[mid] < b) lo = mid + 1; else hi = mid; }
        starts[b] = lo;
    }
}

// ---------------- same-graph edge count ----------------
__global__ void k_edges(const int* __restrict__ ei, const int* __restrict__ batch,
                        int* __restrict__ nedge) {
    int e = blockIdx.x * blockDim.x + threadIdx.x;
    if (e >= Ee) return;
    int s = ei[e], d = ei[Ee + e];
    int gs = batch[s], gd = batch[d];
    if (gs == gd) atomicAdd(&nedge[gs], 1);
}

// ---------------- pooling phase A: partial sums, (graph, chunk) blocks ----------------
// block (b, c): rows {s+c, s+c+PCH, ...}; 256 threads: t<128 -> ggnn float4 col t, t>=128 -> appnp col t-128
// unroll x4 with independent accumulators -> 4 float4 loads in flight per thread
__global__ __launch_bounds__(256) void k_pool_part(const float* __restrict__ xg, const float* __restrict__ xa,
                                                   const int* __restrict__ starts, float* __restrict__ pp) {
    int b = blockIdx.x, c = blockIdx.y;
    int s = starts[b], e = starts[b + 1];
    int t = threadIdx.x;
    int arr = t >> 7, c4 = t & 127;
    const float4* base = (const float4*)(arr ? xa : xg);
    float4 a0 = {0.f,0.f,0.f,0.f}, a1 = a0, a2 = a0, a3 = a0;
    int i = s + c;
    const float4* p = base + (size_t)i * 128 + c4;
    for (; i + 3 * PCH < e; i += 4 * PCH, p += 4 * PCH * 128) {
        float4 v0 = p[0];
        float4 v1 = p[PCH * 128];
        float4 v2 = p[2 * PCH * 128];
        float4 v3 = p[3 * PCH * 128];
        a0.x += v0.x; a0.y += v0.y; a0.z += v0.z; a0.w += v0.w;
        a1.x += v1.x; a1.y += v1.y; a1.z += v1.z; a1.w += v1.w;
        a2.x += v2.x; a2.y += v2.y; a2.z += v2.z; a2.w += v2.w;
        a3.x += v3.x; a3.y += v3.y; a3.z += v3.z; a3.w += v3.w;
    }
    for (; i < e; i += PCH, p += PCH * 128) {
        float4 v = p[0];
        a0.x += v.x; a0.y += v.y; a0.z += v.z; a0.w += v.w;
    }
    float4 acc = {a0.x + a1.x + a2.x + a3.x,
                  a0.y + a1.y + a2.y + a3.y,
                  a0.z + a1.z + a2.z + a3.z,
                  a0.w + a1.w + a2.w + a3.w};
    // partial row layout: [1024] = [ggnn 512 | appnp 512]; slot t == arr*128+c4
    ((float4*)(pp + ((size_t)(c * Bb + b)) * 1024))[t] = acc;
}

// ---------------- pooling phase B: reduce partials, mean, cosine + complexity ----------------
__global__ __launch_bounds__(256) void k_pool_fin(const float* __restrict__ pp, const int* __restrict__ starts,
                                                  const int* __restrict__ nedge, float* __restrict__ g) {
    int b = blockIdx.x, t = threadIdx.x;
    int s = starts[b], e = starts[b + 1];
    int cnt = e - s;
    int arr = t >> 7, c4 = t & 127;
    float4 acc = {0.f,0.f,0.f,0.f};
    #pragma unroll
    for (int c = 0; c < PCH; ++c) {
        float4 u = ((const float4*)(pp + ((size_t)(c * Bb + b)) * 1024))[t];
        acc.x += u.x; acc.y += u.y; acc.z += u.z; acc.w += u.w;
    }
    float inv = 1.0f / (float)(cnt < 1 ? 1 : cnt);
    float4 m = {acc.x * inv, acc.y * inv, acc.z * inv, acc.w * inv};
    float* grow = g + (size_t)b * GIN;
    *(float4*)(grow + arr * Hh + c4 * 4) = m;

    __shared__ float4 sa[128];
    if (arr) sa[c4] = m;
    __syncthreads();
    float d3 = 0.f, ng = 0.f, na = 0.f;
    if (!arr) {
        float4 q = sa[c4];
        d3 = m.x * q.x + m.y * q.y + m.z * q.z + m.w * q.w;
        ng = m.x * m.x + m.y * m.y + m.z * m.z + m.w * m.w;
    } else {
        na = m.x * m.x + m.y * m.y + m.z * m.z + m.w * m.w;
    }
    for (int off = 32; off; off >>= 1) {
        d3 += __shfl_down(d3, off);
        ng += __shfl_down(ng, off);
        na += __shfl_down(na, off);
    }
    __shared__ float r[12];
    int wid = t >> 6, lane = t & 63;
    if (lane == 0) { r[wid * 3] = d3; r[wid * 3 + 1] = ng; r[wid * 3 + 2] = na; }
    __syncthreads();
    if (t == 0) {
        float D  = r[0] + r[3] + r[6] + r[9];
        float NG = r[1] + r[4] + r[7] + r[10];
        float NA = r[2] + r[5] + r[8] + r[11];
        float nag = fmaxf(sqrtf(NG), 1e-8f);
        float nab = fmaxf(sqrtf(NA), 1e-8f);
        float cosv = D / (nag * nab);
        float n  = (float)cnt;
        float ne = (float)nedge[b];
        grow[1024] = logf(n + 1.f) / logf(501.f);              // scale
        grow[1025] = ne / (n * (n - 1.f) + 1e-8f);             // density
        grow[1026] = fminf(ne / (n + 1e-8f) * 0.1f, 1.f);      // avg_degree_norm
        grow[1027] = (1.f - cosv) * 0.5f;                      // divergence
    }
}

// ---------------- GEMM1: h_part = g(512x1028) @ W1(1028x512), split-K=4 ----------------
__global__ __launch_bounds__(256) void k_g1(const float* __restrict__ g, const float* __restrict__ W1,
                                            float* __restrict__ hp) {
    int tj = threadIdx.x & 15, tb = threadIdx.x >> 4;
    int j0 = blockIdx.x * 64 + tj * 4;
    int b0 = blockIdx.y * 64 + tb * 4;
    int kc = blockIdx.z;
    int k = kc * 257, kend = k + 257;
    const float* g0 = g + (size_t)b0 * GIN;
    const float* g1 = g0 + GIN;
    const float* g2 = g1 + GIN;
    const float* g3 = g2 + GIN;
    float4 a0 = {0,0,0,0}, a1 = a0, a2 = a0, a3 = a0;
    for (; k < kend; ++k) {
        float4 w = *(const float4*)(W1 + (size_t)k * Hh + j0);
        float x0 = g0[k], x1 = g1[k], x2 = g2[k], x3 = g3[k];
        a0.x += x0 * w.x; a0.y += x0 * w.y; a0.z += x0 * w.z; a0.w += x0 * w.w;
        a1.x += x1 * w.x; a1.y += x1 * w.y; a1.z += x1 * w.z; a1.w += x1 * w.w;
        a2.x += x2 * w.x; a2.y += x2 * w.y; a2.z += x2 * w.z; a2.w += x2 * w.w;
        a3.x += x3 * w.x; a3.y += x3 * w.y; a3.z += x3 * w.z; a3.w += x3 * w.w;
    }
    float* o = hp + ((size_t)kc * Bb + b0) * Hh + j0;
    *(float4*)(o)           = a0;
    *(float4*)(o + Hh)      = a1;
    *(float4*)(o + 2 * Hh)  = a2;
    *(float4*)(o + 3 * Hh)  = a3;
}

// ---------------- reduce split-K partials + bias + LayerNorm + ReLU ----------------
__global__ __launch_bounds__(128) void k_ln(const float* __restrict__ hp, const float* __restrict__ b1,
                                            const float* __restrict__ lng, const float* __restrict__ lnb,
                                            float* __restrict__ h) {
    int b = blockIdx.x, t = threadIdx.x;
    const float4* p0 = (const float4*)(hp + (size_t)b * Hh);
    const float4* p1 = (const float4*)(hp + ((size_t)Bb + b) * Hh);
    const float4* p2 = (const float4*)(hp + ((size_t)2 * Bb + b) * Hh);
    const float4* p3 = (const float4*)(hp + ((size_t)3 * Bb + b) * Hh);
    float4 v0 = p0[t], v1 = p1[t], v2 = p2[t], v3 = p3[t], bb = ((const float4*)b1)[t];
    float4 v = {v0.x + v1.x + v2.x + v3.x + bb.x,
                v0.y + v1.y + v2.y + v3.y + bb.y,
                v0.z + v1.z + v2.z + v3.z + bb.z,
                v0.w + v1.w + v2.w + v3.w + bb.w};
    float s  = v.x + v.y + v.z + v.w;
    float ss = v.x * v.x + v.y * v.y + v.z * v.z + v.w * v.w;
    for (int off = 32; off; off >>= 1) { s += __shfl_down(s, off); ss += __shfl_down(ss, off); }
    __shared__ float sh[4];
    __shared__ float mus, rs;
    int wid = t >> 6, lane = t & 63;
    if (lane == 0) { sh[wid * 2] = s; sh[wid * 2 + 1] = ss; }
    __syncthreads();
    if (t == 0) {
        float S = sh[0] + sh[2], SS = sh[1] + sh[3];
        float mu = S * (1.f / 512.f);
        float var = SS * (1.f / 512.f) - mu * mu;
        mus = mu; rs = rsqrtf(var + 1e-5f);
    }
    __syncthreads();
    float mu = mus, rstd = rs;
    float4 gg = ((const float4*)lng)[t], be = ((const float4*)lnb)[t];
    float4 o;
    o.x = fmaxf((v.x - mu) * rstd * gg.x + be.x, 0.f);
    o.y = fmaxf((v.y - mu) * rstd * gg.y + be.y, 0.f);
    o.z = fmaxf((v.z - mu) * rstd * gg.z + be.z, 0.f);
    o.w = fmaxf((v.w - mu) * rstd * gg.w + be.w, 0.f);
    ((float4*)(h + (size_t)b * Hh))[t] = o;
}

// ---------------- GEMM2: h(512x512) @ W2(512x256), split-K=2 ----------------
__global__ __launch_bounds__(256) void k_g2(const float* __restrict__ h, const float* __restrict__ W2,
                                            float* __restrict__ hp2) {
    int tj = threadIdx.x & 15, tb = threadIdx.x >> 4;
    int j0 = blockIdx.x * 64 + tj * 4;
    int b0 = blockIdx.y * 64 + tb * 4;
    int kc = blockIdx.z;
    int k = kc * 256, kend = k + 256;
    const float* h0 = h + (size_t)b0 * Hh;
    const float* h1 = h0 + Hh;
    const float* h2 = h1 + Hh;
    const float* h3 = h2 + Hh;
    float4 a0 = {0,0,0,0}, a1 = a0, a2 = a0, a3 = a0;
    for (; k < kend; ++k) {
        float4 w = *(const float4*)(W2 + (size_t)k * 256 + j0);
        float x0 = h0[k], x1 = h1[k], x2 = h2[k], x3 = h3[k];
        a0.x += x0 * w.x; a0.y += x0 * w.y; a0.z += x0 * w.z; a0.w += x0 * w.w;
        a1.x += x1 * w.x; a1.y += x1 * w.y; a1.z += x1 * w.z; a1.w += x1 * w.w;
        a2.x += x2 * w.x; a2.y += x2 * w.y; a2.z += x2 * w.z; a2.w += x2 * w.w;
        a3.x += x3 * w.x; a3.y += x3 * w.y; a3.z += x3 * w.z; a3.w += x3 * w.w;
    }
    float* o = hp2 + ((size_t)kc * Bb + b0) * 256 + j0;
    *(float4*)(o)          = a0;
    *(float4*)(o + 256)    = a1;
    *(float4*)(o + 512)    = a2;
    *(float4*)(o + 768)    = a3;
}

// ---------------- layer2 bias+ReLU, GEMM3 (256x2) + softmax -> per-graph weights ----------------
__global__ __launch_bounds__(64) void k_g3(const float* __restrict__ hp2, const float* __restrict__ b2,
                                           const float* __restrict__ W3, const float* __restrict__ b3,
                                           float* __restrict__ wl, float* __restrict__ wg) {
    int b = blockIdx.x, t = threadIdx.x;
    const float4* p0 = (const float4*)(hp2 + (size_t)b * 256);
    const float4* p1 = (const float4*)(hp2 + ((size_t)Bb + b) * 256);
    float4 v0 = p0[t], v1 = p1[t], bb = ((const float4*)b2)[t];
    float h0 = fmaxf(v0.x + v1.x + bb.x, 0.f);
    float h1 = fmaxf(v0.y + v1.y + bb.y, 0.f);
    float h2 = fmaxf(v0.z + v1.z + bb.z, 0.f);
    float h3 = fmaxf(v0.w + v1.w + bb.w, 0.f);
    int j0 = t * 4;
    float r0 = h0 * W3[j0 * 2]     + h1 * W3[(j0 + 1) * 2]     + h2 * W3[(j0 + 2) * 2]     + h3 * W3[(j0 + 3) * 2];
    float r1 = h0 * W3[j0 * 2 + 1] + h1 * W3[(j0 + 1) * 2 + 1] + h2 * W3[(j0 + 2) * 2 + 1] + h3 * W3[(j0 + 3) * 2 + 1];
    for (int off = 32; off; off >>= 1) { r0 += __shfl_down(r0, off); r1 += __shfl_down(r1, off); }
    if (t == 0) {
        float raw0 = r0 + b3[0], raw1 = r1 + b3[1];
        float mx = fmaxf(raw0, raw1);
        float e0 = expf(raw0 - mx), e1 = expf(raw1 - mx);
        float inv = 1.f / (e0 + e1);
        wl[b] = e0 * inv;
        wg[b] = e1 * inv;
    }
}

// ---------------- final fusion: out = wl[batch]*xg + wg[batch]*xa ----------------
__global__ __launch_bounds__(256) void k_fuse(const float* __restrict__ xg, const float* __restrict__ xa,
                                              const int* __restrict__ batch, const float* __restrict__ wl,
                                              const float* __restrict__ wg, float* __restrict__ out) {
    size_t tid = (size_t)blockIdx.x * 256 + threadIdx.x;
    if (tid >= (size_t)Nn * (Hh / 4)) return;
    int i = (int)(tid >> 7);
    int b = batch[i];
    float l = wl[b], gl = wg[b];
    float4 a = ((const float4*)xg)[tid];
    float4 p = ((const float4*)xa)[tid];
    float4 o = {l * a.x + gl * p.x, l * a.y + gl * p.y, l * a.z + gl * p.z, l * a.w + gl * p.w};
    ((float4*)out)[tid] = o;
}

extern "C" void kernel_launch(void* const* d_in, const int* in_sizes, int n_in,
                              void* d_out, int out_size, void* d_ws, size_t ws_size,
                              hipStream_t stream) {
    const float* xg   = (const float*)d_in[0];
    const float* xa   = (const float*)d_in[1];
    const int*   ei   = (const int*)d_in[2];
    const int*   batch= (const int*)d_in[3];
    const float* W1   = (const float*)d_in[4];
    const float* b1   = (const float*)d_in[5];
    const float* lng  = (const float*)d_in[6];
    const float* lnb  = (const float*)d_in[7];
    const float* W2   = (const float*)d_in[8];
    const float* b2   = (const float*)d_in[9];
    const float* W3   = (const float*)d_in[10];
    const float* b3   = (const float*)d_in[11];
    float* out = (float*)d_out;

    char* ws = (char*)d_ws;
    int*   starts = (int*)(ws + OFF_STARTS);
    int*   nedge  = (int*)(ws + OFF_NEDGE);
    float* wl     = (float*)(ws + OFF_WL);
    float* wg     = (float*)(ws + OFF_WG);
    float* g      = (float*)(ws + OFF_G);
    float* pp     = (float*)(ws + OFF_PP);
    float* hp     = (float*)(ws + OFF_HPART);
    float* h      = (float*)(ws + OFF_H);
    float* hp2    = (float*)(ws + OFF_HP2);

    hipMemsetAsync(nedge, 0, Bb * sizeof(int), stream);
    k_starts<<<1, 256, 0, stream>>>(batch, starts);
    k_edges<<<(Ee + 255) / 256, 256, 0, stream>>>(ei, batch, nedge);
    k_pool_part<<<dim3(Bb, PCH), 256, 0, stream>>>(xg, xa, starts, pp);
    k_pool_fin<<<Bb, 256, 0, stream>>>(pp, starts, nedge, g);
    k_g1<<<dim3(8, 8, 4), 256, 0, stream>>>(g, W1, hp);
    k_ln<<<Bb, 128, 0, stream>>>(hp, b1, lng, lnb, h);
    k_g2<<<dim3(4, 8, 2), 256, 0, stream>>>(h, W2, hp2);
    k_g3<<<Bb, 64, 0, stream>>>(hp2, b2, W3, b3, wl, wg);
    k_fuse<<<(Nn * (Hh / 4) + 255) / 256, 256, 0, stream>>>(xg, xa, batch, wl, wg, out);
}